// Round 13
// baseline (180.294 us; speedup 1.0000x reference)
//
#include <hip/hip_runtime.h>
#include <hip/hip_bf16.h>

typedef unsigned char u8;
typedef float f32x4 __attribute__((ext_vector_type(4)));

#define NB 4096     // batch rows
#define NM 16384    // memory bank rows
#define ND 256      // feature dim (K)
#define CT 160      // col tiles (20480 / 128)
#define RT 32       // row tiles (4096 / 128)

__device__ __forceinline__ float ex2(float x) {
#if __has_builtin(__builtin_amdgcn_exp2f)
    return __builtin_amdgcn_exp2f(x);   // single v_exp_f32
#else
    return exp2f(x);
#endif
}

// float4 -> 4 packed OCP e4m3 bytes (v_cvt_pk_fp8_f32, gfx940+)
__device__ __forceinline__ int f4_to_fp8x4(float4 v) {
    int r = __builtin_amdgcn_cvt_pk_fp8_f32(v.x, v.y, 0, false);   // bytes 0,1
    r = __builtin_amdgcn_cvt_pk_fp8_f32(v.z, v.w, r, true);        // bytes 2,3
    return r;
}

// DPP lane moves within a row of 16 (our reduction group = lane16, q = DPP row)
template<int C>
__device__ __forceinline__ float dppf(float x) {
    int v = __float_as_int(x);
    return __int_as_float(__builtin_amdgcn_update_dpp(v, v, C, 0xF, 0xF, false));
}
template<int C>
__device__ __forceinline__ unsigned dppu(unsigned x) {
    return (unsigned)__builtin_amdgcn_update_dpp((int)x, (int)x, C, 0xF, 0xF, false);
}
#define DPP_XOR1 0xB1   // quad_perm [1,0,3,2]
#define DPP_XOR2 0x4E   // quad_perm [2,3,0,1]
#define DPP_ROR4 0x124  // row_ror:4
#define DPP_ROR8 0x128  // row_ror:8

__device__ __forceinline__ void gld_lds16(const u8* g, u8* l) {
    __builtin_amdgcn_global_load_lds((__attribute__((address_space(1))) void*)g,
                                     (__attribute__((address_space(3))) void*)l,
                                     16, 0, 0);
}

// ---- fused prep: normalize f1/f2 (fp32 + fp8), convert banks to fp8 --------
// blocks 0..2047: norm (4 rows each). blocks 2048..10239: bank conversion
// (8192 conv blocks = 2,097,152 float4s = BOTH banks; R11's 4096 left mb2n
// poisoned).
__global__ __launch_bounds__(256) void prep(
    const float* __restrict__ if1, const float* __restrict__ if2,
    const float* __restrict__ mb1, const float* __restrict__ mb2,
    float* __restrict__ f1f, float* __restrict__ f2f,
    u8* __restrict__ f1n, u8* __restrict__ f2n,
    u8* __restrict__ mb1n, u8* __restrict__ mb2n,
    unsigned* __restrict__ Mpack, float* __restrict__ accum)
{
    const int b = blockIdx.x, t = threadIdx.x;
    if (b == 0 && t < 8) accum[t] = 0.f;        // sums + counter
    if (b < 32) Mpack[b * 256 + t] = 0u;        // [2*NB] = 8192 for atomicMax
    if (b < 2048) {
        const int wave = t >> 6, lane = t & 63;
        const int g = b * 4 + wave;         // 0..8191
        const float* in; float* of; u8* ob; int row;
        if (g < NB) { in = if1; of = f1f; ob = f1n; row = g; }
        else        { in = if2; of = f2f; ob = f2n; row = g - NB; }
        float4 v = ((const float4*)(in + (size_t)row * ND))[lane];
        float ss = v.x*v.x + v.y*v.y + v.z*v.z + v.w*v.w;
        #pragma unroll
        for (int off = 1; off < 64; off <<= 1) ss += __shfl_xor(ss, off, 64);
        float inv = 1.0f / fmaxf(sqrtf(ss), 1e-12f);
        float4 o = make_float4(v.x*inv, v.y*inv, v.z*inv, v.w*inv);
        ((float4*)(of + (size_t)row * ND))[lane] = o;
        ((int*)ob)[row * 64 + lane] = f4_to_fp8x4(o);
    } else {
        size_t i = (size_t)(b - 2048) * 256 + t;      // float4 index, 0..2M
        const float* in; u8* ob; size_t idx;
        if (i < (size_t)NM * 64) { in = mb1; ob = mb1n; idx = i; }
        else { in = mb2; ob = mb2n; idx = i - (size_t)NM * 64; }
        float4 v = ((const float4*)in)[idx];
        ((int*)ob)[idx] = f4_to_fp8x4(v);
    }
}

// ---- fused GEMM (plain fp8 K=32) + (sum-exp, packed max/argmax) epilogue ---
// grid: (160 coltiles, 32 rowtiles, 2 matmuls), block 256 (4 waves, 2x2).
// Block tile 128x128, fp8 e4m3, mfma_f32_16x16x32_fp8_fp8: 2-reg (8 B)
// operands = single ds_read_b64 each -> no i32x8 rebuilds (R12's VALU tax),
// live set ~105 regs -> launch_bounds(256,4) = 4 blocks/CU without spill
// (R7/R9 rule: acc + working <= 2048 / waves-per-CU).
// LDS rows = 128 B = 8 x 16B chunks, XOR-swizzled (slot s holds global chunk
// s^(row&7)); lane (q,l16) step kk reads 8 B at chunk 2kk+(q>>1), half q&1.
// Epilogue pack: bits(e) monotone for e>0; bfi idiom = 1 inst/value;
// decode via log2f in finalize. Z via coalesced Zpart stores; max/argmax
// via one atomicMax/row.
__global__ __launch_bounds__(256, 4) void gemm_nce(
    const u8* __restrict__ f1n, const u8* __restrict__ f2n,
    const u8* __restrict__ mb1n, const u8* __restrict__ mb2n,
    const float* __restrict__ scale_ptr,
    float* __restrict__ Zpart,      // [2][CT][NB]
    unsigned* __restrict__ Mpack)   // [2][NB]
{
    __shared__ __attribute__((aligned(16))) u8 As[128 * 128];   // 16 KB
    __shared__ __attribute__((aligned(16))) u8 Bs[128 * 128];   // 16 KB
    // reduction scratch aliases As (dead after K-loop tail barrier): 2 KB
    float    (*redsum)[128] = (float(*)[128])As;
    unsigned (*redpak)[128] = (unsigned(*)[128])(As + 1024);

    const int ctile = blockIdx.x, rtile = blockIdx.y, z = blockIdx.z;
    const u8* A  = (z ? f2n : f1n) + (size_t)rtile * 128 * ND;
    const u8* Bp = (ctile < 32) ? ((z ? f1n : f2n) + (size_t)ctile * 128 * ND)
                                 : ((z ? mb1n : mb2n) + (size_t)(ctile - 32) * 128 * ND);
    const int t = threadIdx.x;
    const int wave = t >> 6, lane = t & 63;
    const int wr = wave >> 1, wc = wave & 1;
    const int lane16 = lane & 15, q = lane >> 4;
    const int srow = t >> 3;                        // 0..31 staged row
    const int cg = (t & 7) ^ (srow & 7);            // swizzled global chunk

    f32x4 acc[4][4] = {};

    // Per-fragment row bases (fixed across kt/kk): row, its swizzle key, and
    // the in-chunk byte half for this lane.
    const int half8 = (q & 1) * 8, cbase = q >> 1;

    #pragma unroll
    for (int kt = 0; kt < 2; ++kt) {
        const u8* ga = A  + (size_t)srow * ND + kt * 128 + cg * 16;
        const u8* gb = Bp + (size_t)srow * ND + kt * 128 + cg * 16;
        u8* la = As + t * 16;
        u8* lb = Bs + t * 16;
        #pragma unroll
        for (int ch = 0; ch < 4; ++ch) {    // 128 rows in 32-row strides
            gld_lds16(ga + (size_t)ch * 32 * ND, la + ch * 4096);
            gld_lds16(gb + (size_t)ch * 32 * ND, lb + ch * 4096);
        }
        __syncthreads();   // drains vmcnt (global_load_lds) before LDS reads
        #pragma unroll
        for (int kk = 0; kk < 4; ++kk) {    // K=32 steps
            const int cwant = 2 * kk + cbase;       // desired global chunk
            long long bv[4];
            #pragma unroll
            for (int j = 0; j < 4; ++j) {
                int rb = wc*64 + j*16 + lane16;
                int c = cwant ^ (rb & 7);
                bv[j] = *(const long long*)(Bs + rb*128 + c*16 + half8);
            }
            #pragma unroll
            for (int i = 0; i < 4; ++i) {
                int ra = wr*64 + i*16 + lane16;
                int c = cwant ^ (ra & 7);
                long long av = *(const long long*)(As + ra*128 + c*16 + half8);
                #pragma unroll
                for (int j = 0; j < 4; ++j)
                    acc[i][j] = __builtin_amdgcn_mfma_f32_16x16x32_fp8_fp8(
                        av, bv[j], acc[i][j], 0, 0, 0);
            }
        }
        __syncthreads();
    }
    // As now dead as tile storage; redsum/redpak live in it from here on.

    const float scale = *scale_ptr;
    const float kl = scale * 1.44269504088896f;  // scale * log2(e)
    const bool doicel = (ctile >= 32);

    unsigned cpack[4];
    #pragma unroll
    for (int j = 0; j < 4; ++j) cpack[j] = 127 - (j * 16 + lane16);

    // C/D layout (m89/m91, dtype-independent): col = lane&15, row = q*4 + r
    #pragma unroll
    for (int i = 0; i < 4; ++i) {
        #pragma unroll
        for (int r = 0; r < 4; ++r) {
            float e0 = ex2(kl * acc[i][0][r]), e1 = ex2(kl * acc[i][1][r]),
                  e2 = ex2(kl * acc[i][2][r]), e3 = ex2(kl * acc[i][3][r]);
            float e = (e0 + e1) + (e2 + e3);
            e += dppf<DPP_XOR1>(e);
            e += dppf<DPP_XOR2>(e);
            e += dppf<DPP_ROR4>(e);
            e += dppf<DPP_ROR8>(e);
            unsigned p = 0;
            if (doicel) {
                // pack = (bits(e) & ~0x7F) | (127-col): e>0 => bit-order =
                // value-order; ties -> larger cpack = LOWER col. bfi idiom.
                unsigned p0 = (0x7Fu & cpack[0]) | (~0x7Fu & __float_as_uint(e0));
                unsigned p1 = (0x7Fu & cpack[1]) | (~0x7Fu & __float_as_uint(e1));
                unsigned p2 = (0x7Fu & cpack[2]) | (~0x7Fu & __float_as_uint(e2));
                unsigned p3 = (0x7Fu & cpack[3]) | (~0x7Fu & __float_as_uint(e3));
                p = max(max(p0, p1), max(p2, p3));
                p = max(p, dppu<DPP_XOR1>(p));
                p = max(p, dppu<DPP_XOR2>(p));
                p = max(p, dppu<DPP_ROR4>(p));
                p = max(p, dppu<DPP_ROR8>(p));
            }
            if (lane16 == 0) {
                int rl = wr*64 + i*16 + q*4 + r;
                redsum[wc][rl] = e;
                redpak[wc][rl] = p;
            }
        }
    }
    __syncthreads();
    if (t < 128) {
        int grow = rtile * 128 + t;
        Zpart[((size_t)z * CT + ctile) * NB + grow] = redsum[0][t] + redsum[1][t];
        if (doicel) {
            unsigned q0 = redpak[0][t], q1 = redpak[1][t];
            int c0 = 127 - (int)(q0 & 127);   // col within wc=0 half (0..63)
            int c1 = 127 - (int)(q1 & 127);
            int cb = (ctile - 32) * 128;
            unsigned g0 = (q0 & 0xFFFFC000u) | (unsigned)(16383 - (cb + c0));
            unsigned g1 = (q1 & 0xFFFFC000u) | (unsigned)(16383 - (cb + 64 + c1));
            unsigned g = g0 > g1 ? g0 : g1;   // equal-val tie -> lower gcol wins
            atomicMax(&Mpack[z * NB + grow], g);
        }
    }
}

// ---- finalize: Z-reduce + decode argmax + gather + MSE/CE + combine --------
// 256 blocks x 256 threads: 16 rows/block. (fp32 banks -> exact MSE/diag.)
__global__ __launch_bounds__(256) void finalize4(
    const float* __restrict__ Zpart, const unsigned* __restrict__ Mpack,
    const float* __restrict__ f1f, const float* __restrict__ f2f,
    const float* __restrict__ mb1, const float* __restrict__ mb2,
    const float* __restrict__ scale_ptr, float* __restrict__ accum,
    float* __restrict__ out)
{
    __shared__ float zp[2][16][16];   // [z][cidx][row_l]
    __shared__ float Zr[2][16];
    __shared__ float lds5[16][5];
    const int t = threadIdx.x, g = t >> 4, l16 = t & 15;
    const int base = blockIdx.x * 16;

    // Phase A: Z partial sums, coalesced (lanes along rows)
    {
        const int row_l = t & 15, cidx = t >> 4;
        #pragma unroll
        for (int z = 0; z < 2; ++z) {
            float s = 0.f;
            #pragma unroll
            for (int c = cidx * 10; c < cidx * 10 + 10; ++c)
                s += Zpart[((size_t)z * CT + c) * NB + base + row_l];
            zp[z][cidx][row_l] = s;
        }
    }
    __syncthreads();
    if (t < 32) {
        int z = t >> 4, rl = t & 15;
        float s = 0.f;
        #pragma unroll
        for (int k = 0; k < 16; ++k) s += zp[z][k][rl];
        Zr[z][rl] = s;
    }
    __syncthreads();

    const int row = base + g;
    const float scale = *scale_ptr;
    const float kl = scale * 1.44269504088896f;

    unsigned mp1 = Mpack[row], mp2 = Mpack[NB + row];
    int a1 = 16383 - (int)(mp1 & 16383u);
    int a2 = 16383 - (int)(mp2 & 16383u);
    // value field = truncated bits(e); m = log2(e)/kl (e>0 normal)
    float m1 = log2f(__uint_as_float(mp1 & 0xFFFFC000u)) / kl;
    float m2 = log2f(__uint_as_float(mp2 & 0xFFFFC000u)) / kl;

    const float4* x1p = (const float4*)(f1f + (size_t)row * ND);
    const float4* x2p = (const float4*)(f2f + (size_t)row * ND);
    const float4* y1p = (const float4*)(mb2 + (size_t)a1 * ND);
    const float4* y2p = (const float4*)(mb1 + (size_t)a2 * ND);
    float d = 0.f, sq1 = 0.f, sq2 = 0.f;
    #pragma unroll
    for (int k = 0; k < 4; ++k) {
        int idx = k * 16 + l16;
        float4 x1 = x1p[idx], x2 = x2p[idx], y1 = y1p[idx], y2 = y2p[idx];
        d += x1.x*x2.x + x1.y*x2.y + x1.z*x2.z + x1.w*x2.w;
        float dx = x1.x-y1.x, dy = x1.y-y1.y, dz = x1.z-y1.z, dw = x1.w-y1.w;
        sq1 += dx*dx + dy*dy + dz*dz + dw*dw;
        dx = x2.x-y2.x; dy = x2.y-y2.y; dz = x2.z-y2.z; dw = x2.w-y2.w;
        sq2 += dx*dx + dy*dy + dz*dz + dw*dw;
    }
    #pragma unroll
    for (int off = 1; off < 16; off <<= 1) {
        d   += __shfl_xor(d,   off, 16);
        sq1 += __shfl_xor(sq1, off, 16);
        sq2 += __shfl_xor(sq2, off, 16);
    }
    if (l16 == 0) {
        bool k1 = m1 > 0.2f, k2 = m2 > 0.2f;
        lds5[g][0] = logf(Zr[0][g]) + logf(Zr[1][g]) - 2.f * scale * d;
        lds5[g][1] = k1 ? sq1 : 0.f;
        lds5[g][2] = k1 ? 1.f : 0.f;
        lds5[g][3] = k2 ? sq2 : 0.f;
        lds5[g][4] = k2 ? 1.f : 0.f;
    }
    __syncthreads();
    if (t < 5) {
        float s = 0.f;
        #pragma unroll
        for (int r = 0; r < 16; ++r) s += lds5[r][t];
        atomicAdd(&accum[t], s);
    }
    __syncthreads();
    if (t == 0) {
        __threadfence();
        int old = atomicAdd((int*)(accum + 5), 1);
        if (old == (int)gridDim.x - 1) {        // last block: combine
            __threadfence();
            float a0 = atomicAdd(&accum[0], 0.f);
            float a1v = atomicAdd(&accum[1], 0.f);
            float a2v = atomicAdd(&accum[2], 0.f);
            float a3v = atomicAdd(&accum[3], 0.f);
            float a4v = atomicAdd(&accum[4], 0.f);
            float nce = 0.5f * a0 / (float)NB;
            float icel1 = a2v > 0.f ? a1v / (a2v * (float)ND) : 0.f;
            float icel2 = a4v > 0.f ? a3v / (a4v * (float)ND) : 0.f;
            out[0] = nce + 0.25f * (icel1 + icel2);   // LAMBDA_ICEL = 0.5
        }
    }
}

extern "C" void kernel_launch(void* const* d_in, const int* in_sizes, int n_in,
                              void* d_out, int out_size, void* d_ws, size_t ws_size,
                              hipStream_t stream) {
    const float* if1   = (const float*)d_in[0];
    const float* if2   = (const float*)d_in[1];
    const float* scale = (const float*)d_in[2];
    const float* mb1   = (const float*)d_in[3];
    const float* mb2   = (const float*)d_in[4];
    float* out = (float*)d_out;

    unsigned char* w = (unsigned char*)d_ws;
    size_t off = 0;
    auto alloc = [&](size_t bytes) {
        void* p = w + off;
        off += (bytes + 255) & ~(size_t)255;
        return p;
    };
    u8*       f1n   = (u8*)      alloc((size_t)NB * ND);
    u8*       f2n   = (u8*)      alloc((size_t)NB * ND);
    u8*       mb1n  = (u8*)      alloc((size_t)NM * ND);
    u8*       mb2n  = (u8*)      alloc((size_t)NM * ND);
    float*    f1f   = (float*)   alloc((size_t)NB * ND * 4);
    float*    f2f   = (float*)   alloc((size_t)NB * ND * 4);
    float*    Zpart = (float*)   alloc((size_t)2 * CT * NB * 4);
    unsigned* Mpack = (unsigned*)alloc((size_t)2 * NB * 4);
    float*    accum = (float*)   alloc(256);

    prep<<<dim3(10240), 256, 0, stream>>>(if1, if2, mb1, mb2,
                                          f1f, f2f, f1n, f2n, mb1n, mb2n,
                                          Mpack, accum);
    gemm_nce<<<dim3(CT, RT, 2), 256, 0, stream>>>(f1n, f2n, mb1n, mb2n, scale,
                                                  Zpart, Mpack);
    finalize4<<<dim3(NB / 16), 256, 0, stream>>>(Zpart, Mpack,
                                                 f1f, f2f, mb1, mb2, scale,
                                                 accum, out);
}